// Round 1
// baseline (183.015 us; speedup 1.0000x reference)
//
#include <hip/hip_runtime.h>

// CSR SpMV: y[i] = sum_{j in [rp[i], rp[i+1])} vals[j] * x[cols[j]]
// ROWS = COLS = 1e6, exactly 32 nnz per row (uniform row_ptrs).
//
// Strategy: 8 lanes per row. Each lane does one float4/int4 load
// (16 B/lane -> 1 KiB per wave per instruction, fully coalesced over the
// contiguous values/col_indices streams), 4 gathered x loads (x is 4 MB,
// L2/L3 resident), then a 3-step shfl_xor reduce within the 8-lane group.

__global__ __launch_bounds__(256) void spmv_csr32_kernel(
    const float* __restrict__ x,
    const float* __restrict__ vals,
    const int*   __restrict__ cols,
    const int*   __restrict__ rp,
    float*       __restrict__ y,
    int rows)
{
    const int tid   = blockIdx.x * blockDim.x + threadIdx.x;
    const int row   = tid >> 3;   // 8 threads per row
    const int lane8 = tid & 7;
    if (row >= rows) return;

    const int start = rp[row];
    const int end   = rp[row + 1];

    float sum = 0.0f;
    if (end - start == 32) {
        const int j = start + lane8 * 4;
        const float4 v = *reinterpret_cast<const float4*>(vals + j);
        const int4   c = *reinterpret_cast<const int4*>(cols + j);
        sum = v.x * x[c.x] + v.y * x[c.y] + v.z * x[c.z] + v.w * x[c.w];
    } else {
        // general-CSR fallback (not hit for this input)
        for (int k = start + lane8; k < end; k += 8)
            sum += vals[k] * x[cols[k]];
    }

    // reduce across the 8-lane group
    sum += __shfl_xor(sum, 1);
    sum += __shfl_xor(sum, 2);
    sum += __shfl_xor(sum, 4);

    if (lane8 == 0) y[row] = sum;
}

extern "C" void kernel_launch(void* const* d_in, const int* in_sizes, int n_in,
                              void* d_out, int out_size, void* d_ws, size_t ws_size,
                              hipStream_t stream)
{
    const float* x    = (const float*)d_in[0];
    const float* vals = (const float*)d_in[1];
    const int*   cols = (const int*)d_in[2];
    const int*   rp   = (const int*)d_in[3];
    float*       y    = (float*)d_out;

    const int rows = out_size;              // 1,000,000
    const int threads = rows * 8;           // 8 lanes per row
    const int block = 256;
    const int grid = (threads + block - 1) / block;

    spmv_csr32_kernel<<<grid, block, 0, stream>>>(x, vals, cols, rp, y, rows);
}